// Round 8
// baseline (987.432 us; speedup 1.0000x reference)
//
#include <hip/hip_runtime.h>

#define C_IN 4
#define NF 16
#define TAPS 36               // K * C_IN
#define QS16 16384.0f         // u16 general-path time quantization
#define BSHIFT 11             // 2048 ids per block-table entry
#define BSIZE 2048
#define NBMAX 1024            // supports n_in <= 2^21
#define P 4                   // outputs per thread
#define BLOCK 256
#define OPB (P * BLOCK)       // outputs per block = 1024

typedef int   int4v   __attribute__((ext_vector_type(4)));
typedef float float4v __attribute__((ext_vector_type(4)));
typedef unsigned short u16;
typedef unsigned char  u8;
typedef unsigned int   u32;

// softplus(x)*log2(e), stable — identical in all kernels (mode consistency)
__device__ __forceinline__ float softplus_log2e(float x) {
    return (fmaxf(x, 0.0f) + log1pf(expf(-fabsf(x)))) * 1.4426950408889634f;
}
__device__ __forceinline__ void decay_d2(const float* __restrict__ dr, float* d2) {
#pragma unroll
    for (int c = 0; c < C_IN; ++c) d2[c] = softplus_log2e(dr[c]);
}
__device__ __forceinline__ bool decay_uniform(const float* d2, int n_in) {
    return (d2[0] == d2[1]) & (d2[1] == d2[2]) & (d2[2] == d2[3]) &
           (d2[0] <= 2.0f) & (n_in >= 2);
}
__device__ __forceinline__ int Fof(float t) {   // floor(256*t), clamped
    int q = (int)(t * 256.0f);
    return q < 0 ? 0 : (q > 255 ? 255 : q);
}

// ws layout:
//   u32 aux[0]            : mode (0 = LDS block table, 1 = u8 gather, 2 = u16 gather)
//   u32 aux[1..1+NBMAX)   : block table (mode 0)
//   byte TAB_OFF=4352 ... : gather table (u8 mode 1 / u16 mode 2)
#define TAB_OFF 4352

__global__ __launch_bounds__(256) void btab_build_kernel(
    const float* __restrict__ times_in,
    const float* __restrict__ decay_rate,
    u32*         __restrict__ aux,
    int n_in)
{
    float d2[C_IN];
    decay_d2(decay_rate, d2);
    const int tid = threadIdx.x;
    if (!decay_uniform(d2, n_in)) {
        if (tid == 0) aux[0] = 2u;
        return;
    }
    __shared__ int ls_start[257];
    __shared__ int s_bad;
    if (tid == 0) s_bad = 0;
    if (tid < 256) {                   // first id with Fof(times_in[id]) >= q
        const int q = tid;
        int lo = 0, hi = n_in;
        while (lo < hi) {
            int mid = (lo + hi) >> 1;
            if (Fof(times_in[mid]) >= q) hi = mid; else lo = mid + 1;
        }
        ls_start[q] = lo;
    }
    __syncthreads();
    const int nb = (n_in + BSIZE - 1) >> BSHIFT;
    for (int i = tid; i < nb && i < NBMAX; i += blockDim.x) {
        const int s = i << BSHIFT;
        const int e = min(s + BSIZE, n_in) - 1;
        const int base = Fof(times_in[s]);
        const int endq = Fof(times_in[e]);
        u32 entry;
        if (endq == base) {
            entry = (u32)base | ((u32)BSIZE << 8);            // no breakpoint
        } else if (endq == base + 1) {
            entry = (u32)base | ((u32)(ls_start[base + 1] - s) << 8);
        } else {
            entry = 0; s_bad = 1;                             // multi-breakpoint
        }
        aux[1 + i] = entry;
    }
    __syncthreads();
    if (tid == 0) aux[0] = (nb <= NBMAX && !s_bad) ? 0u : 1u;
}

// Builds the per-id gather table ONLY when mode != 0 (early-exit otherwise).
__global__ __launch_bounds__(256) void fill_tab_kernel(
    const float* __restrict__ times_in,
    const int*   __restrict__ seg_ids,
    const u32*   __restrict__ aux,
    u8*          __restrict__ tab,
    int n_in)
{
    const u32 mode = aux[0];
    if (mode == 0u) return;
    int i = blockIdx.x * blockDim.x + threadIdx.x;
    int stride = gridDim.x * blockDim.x;
    if (mode == 1u) {
        for (; i < n_in; i += stride) {
            float t = times_in[i];
            unsigned q = (unsigned)(t * 256.0f);
            if (q > 255u) q = 255u;
            tab[i] = (u8)q;
        }
    } else {
        u16* t16 = (u16*)tab;
        for (; i < n_in; i += stride) {
            float t = times_in[i];
            unsigned q = (unsigned)(t * QS16);
            if (q > 16383u) q = 16383u;
            t16[i] = (u16)((q << 2) | ((unsigned)seg_ids[i] & 3u));
        }
    }
}

template<bool USE_TABLE>
__global__ __launch_bounds__(256, 3) void onehot_conv_kernel(
    const u8*    __restrict__ tab,
    const u32*   __restrict__ aux,
    const float* __restrict__ times_in,
    const int*   __restrict__ seg_ids,
    const float* __restrict__ times_out,
    const int*   __restrict__ pred_ids,      // (n_out, K, C_IN)
    const float* __restrict__ decay_rate,    // (C_IN,) uniform
    const float* __restrict__ kern,          // (K, C_IN, F)
    const float* __restrict__ bias,          // (F,)    uniform
    float*       __restrict__ out,           // (n_out, F)
    int n_in, int n_out)
{
    __shared__ float s_kern[TAPS * NF];      // 2304 B, broadcast reads
    __shared__ u32   s_btab[NBMAX];          // 4 KB block table (mode 0)

    const int tid = threadIdx.x;
    float d2[C_IN];
    decay_d2(decay_rate, d2);

    const u32 mode = USE_TABLE ? aux[0] : 2u;   // wave-uniform

    for (int i = tid; i < TAPS * NF; i += blockDim.x) s_kern[i] = kern[i];
    if (mode == 0u) {
        const int nb = (n_in + BSIZE - 1) >> BSHIFT;
        for (int i = tid; i < nb; i += blockDim.x) s_btab[i] = aux[1 + i];
    }
    __syncthreads();

    const int base = blockIdx.x * OPB + tid;

    if (mode == 0u) {
        // ---- fast path: P=4 outputs/thread, LDS block table, zero gathers
        const float D = d2[0];
        const float dscale = D * (1.0f / 256.0f);
        float dbase[P];
        float acc[P][NF];
        const int4v* pp[P];
        bool ok[P];
#pragma unroll
        for (int k = 0; k < P; ++k) {
            const int o = base + k * BLOCK;
            ok[k] = (o < n_out);
            const float to = ok[k] ? __builtin_nontemporal_load(times_out + o) : 0.0f;
            dbase[k] = D * (0.5f / 256.0f) - D * to;
            pp[k] = reinterpret_cast<const int4v*>(pred_ids + (size_t)o * TAPS);
#pragma unroll
            for (int f = 0; f < NF; ++f) acc[k][f] = bias[f];
        }
#pragma unroll
        for (int q = 0; q < TAPS / 4; ++q) {
            int4v idv[P];
#pragma unroll
            for (int k = 0; k < P; ++k)
                idv[k] = ok[k] ? __builtin_nontemporal_load(pp[k] + q)
                               : (int4v){ n_in, n_in, n_in, n_in };
#pragma unroll
            for (int j = 0; j < 4; ++j) {
                const int tap = q * 4 + j;
                float w[P];
#pragma unroll
                for (int k = 0; k < P; ++k) {
                    const int id = idv[k][j];
                    const bool valid = (u32)id < (u32)n_in;
                    const int idc = valid ? id : 0;
                    const u32 e = s_btab[idc >> BSHIFT];
                    const u32 uu = (e & 0xFFu) +
                        (((u32)(idc & (BSIZE - 1)) >= (e >> 8)) ? 1u : 0u);
                    w[k] = valid ? exp2f(fmaf((float)uu, dscale, dbase[k])) : 0.0f;
                }
                const float4v* kr = reinterpret_cast<const float4v*>(&s_kern[tap * NF]);
#pragma unroll
                for (int r = 0; r < 4; ++r) {
                    const float4v k4 = kr[r];     // one broadcast read, 16 FMAs
#pragma unroll
                    for (int k = 0; k < P; ++k) {
                        acc[k][r*4+0] = fmaf(w[k], k4.x, acc[k][r*4+0]);
                        acc[k][r*4+1] = fmaf(w[k], k4.y, acc[k][r*4+1]);
                        acc[k][r*4+2] = fmaf(w[k], k4.z, acc[k][r*4+2]);
                        acc[k][r*4+3] = fmaf(w[k], k4.w, acc[k][r*4+3]);
                    }
                }
            }
        }
#pragma unroll
        for (int k = 0; k < P; ++k) {
            if (!ok[k]) continue;
            const int o = base + k * BLOCK;
            float4v* op = reinterpret_cast<float4v*>(out + (size_t)o * NF);
#pragma unroll
            for (int r = 0; r < 4; ++r) {
                float4v v = { acc[k][r*4+0], acc[k][r*4+1], acc[k][r*4+2], acc[k][r*4+3] };
                op[r] = v;
            }
        }
        return;
    }

    // ---- cold paths (mode 1 / mode 2 / no-table): sequential per-output, r7-proven
    for (int k = 0; k < P; ++k) {
        const int o = base + k * BLOCK;
        if (o >= n_out) continue;
        const float t_out = times_out[o];
        float acc[NF];
#pragma unroll
        for (int f = 0; f < NF; ++f) acc[f] = bias[f];
        const int4v* pids = reinterpret_cast<const int4v*>(pred_ids + (size_t)o * TAPS);
        int4v vq[TAPS / 4];
#pragma unroll
        for (int q = 0; q < TAPS / 4; ++q) vq[q] = pids[q];

        if (mode == 1u) {
            const float D = d2[0];
            const float dscale = D * (1.0f / 256.0f);
            const float dbase  = D * (0.5f / 256.0f) - D * t_out;
            unsigned uu[TAPS];
#pragma unroll
            for (int tap = 0; tap < TAPS; ++tap) {
                const int id = vq[tap >> 2][tap & 3];
                const int p  = ((u32)id < (u32)n_in) ? id : (n_in - 1);
                uu[tap] = tab[p];
            }
#pragma unroll
            for (int tap = 0; tap < TAPS; ++tap) {
                const int id = vq[tap >> 2][tap & 3];
                const bool valid = (u32)id < (u32)n_in;
                const float w = valid ? exp2f(fmaf((float)uu[tap], dscale, dbase)) : 0.0f;
                const float4v* kr = reinterpret_cast<const float4v*>(&s_kern[tap * NF]);
#pragma unroll
                for (int r = 0; r < 4; ++r) {
                    float4v k4 = kr[r];
                    acc[r*4+0] = fmaf(w, k4.x, acc[r*4+0]);
                    acc[r*4+1] = fmaf(w, k4.y, acc[r*4+1]);
                    acc[r*4+2] = fmaf(w, k4.z, acc[r*4+2]);
                    acc[r*4+3] = fmaf(w, k4.w, acc[r*4+3]);
                }
            }
        } else {
            const u16* t16 = (const u16*)tab;
            unsigned uu[TAPS];
#pragma unroll
            for (int tap = 0; tap < TAPS; ++tap) {
                const int id = vq[tap >> 2][tap & 3];
                const int p  = ((u32)id < (u32)n_in) ? id : (n_in - 1);
                if (USE_TABLE) {
                    uu[tap] = t16[p];
                } else {
                    float t = times_in[p];
                    unsigned q = (unsigned)(t * QS16);
                    if (q > 16383u) q = 16383u;
                    uu[tap] = (q << 2) | ((unsigned)seg_ids[p] & 3u);
                }
            }
#pragma unroll
            for (int tap = 0; tap < TAPS; ++tap) {
                const int id = vq[tap >> 2][tap & 3];
                const bool valid = (u32)id < (u32)n_in;
                const unsigned u = uu[tap];
                const int c = (int)(u & 3u);
                const float t = (float)(u >> 2) * (1.0f / QS16) + (0.5f / QS16);
                const float dd = (c & 2) ? ((c & 1) ? d2[3] : d2[2])
                                         : ((c & 1) ? d2[1] : d2[0]);
                const float w = valid ? exp2f(-dd * (t_out - t)) : 0.0f;
                const float4v* kr = reinterpret_cast<const float4v*>(&s_kern[tap * NF]);
#pragma unroll
                for (int r = 0; r < 4; ++r) {
                    float4v k4 = kr[r];
                    acc[r*4+0] = fmaf(w, k4.x, acc[r*4+0]);
                    acc[r*4+1] = fmaf(w, k4.y, acc[r*4+1]);
                    acc[r*4+2] = fmaf(w, k4.z, acc[r*4+2]);
                    acc[r*4+3] = fmaf(w, k4.w, acc[r*4+3]);
                }
            }
        }
        float4v* op = reinterpret_cast<float4v*>(out + (size_t)o * NF);
#pragma unroll
        for (int r = 0; r < 4; ++r) {
            float4v v = { acc[r*4+0], acc[r*4+1], acc[r*4+2], acc[r*4+3] };
            op[r] = v;
        }
    }
}

extern "C" void kernel_launch(void* const* d_in, const int* in_sizes, int n_in_arrs,
                              void* d_out, int out_size, void* d_ws, size_t ws_size,
                              hipStream_t stream) {
    (void)n_in_arrs; (void)out_size;
    const float* times_in   = (const float*)d_in[0];
    const float* times_out  = (const float*)d_in[1];
    const int*   seg_ids    = (const int*)d_in[2];
    const int*   pred_ids   = (const int*)d_in[3];
    const float* decay_rate = (const float*)d_in[4];
    const float* kern       = (const float*)d_in[5];
    const float* bias       = (const float*)d_in[6];

    const int n_in  = in_sizes[0];
    const int n_out = in_sizes[1];

    float* out = (float*)d_out;

    const int grid = (n_out + OPB - 1) / OPB;
    const size_t need = (size_t)TAB_OFF + (size_t)n_in * 2;

    if (ws_size >= need) {
        u32* aux = (u32*)d_ws;
        u8*  tab = (u8*)d_ws + TAB_OFF;
        btab_build_kernel<<<1, 256, 0, stream>>>(times_in, decay_rate, aux, n_in);
        fill_tab_kernel<<<2048, 256, 0, stream>>>(times_in, seg_ids, aux, tab, n_in);
        onehot_conv_kernel<true><<<grid, BLOCK, 0, stream>>>(
            tab, aux, times_in, seg_ids, times_out, pred_ids,
            decay_rate, kern, bias, out, n_in, n_out);
    } else {
        onehot_conv_kernel<false><<<grid, BLOCK, 0, stream>>>(
            nullptr, nullptr, times_in, seg_ids, times_out, pred_ids,
            decay_rate, kern, bias, out, n_in, n_out);
    }
}

// Round 9
// 748.553 us; speedup vs baseline: 1.3191x; 1.3191x over previous
//
#include <hip/hip_runtime.h>

#define C_IN 4
#define NF 16
#define TAPS 36               // K * C_IN
#define QS16 16384.0f         // u16 general-path time quantization
#define BSHIFT 11             // 2048 ids per block-table entry
#define BSIZE 2048
#define NBMAX 1024            // supports n_in <= 2^21
#define P 2                   // outputs per thread (fast path, full tiles)
#define BLOCK 256
#define OPB (P * BLOCK)       // 512 outputs per full block

typedef int   int4v   __attribute__((ext_vector_type(4)));
typedef float float4v __attribute__((ext_vector_type(4)));
typedef float float2v __attribute__((ext_vector_type(2)));
typedef unsigned short u16;
typedef unsigned char  u8;
typedef unsigned int   u32;

// softplus(x)*log2(e), stable — identical in all kernels (mode consistency)
__device__ __forceinline__ float softplus_log2e(float x) {
    return (fmaxf(x, 0.0f) + log1pf(expf(-fabsf(x)))) * 1.4426950408889634f;
}
__device__ __forceinline__ void decay_d2(const float* __restrict__ dr, float* d2) {
#pragma unroll
    for (int c = 0; c < C_IN; ++c) d2[c] = softplus_log2e(dr[c]);
}
__device__ __forceinline__ bool decay_uniform(const float* d2, int n_in) {
    return (d2[0] == d2[1]) & (d2[1] == d2[2]) & (d2[2] == d2[3]) &
           (d2[0] <= 2.0f) & (n_in >= 2);
}
__device__ __forceinline__ int Fof(float t) {   // floor(256*t), clamped
    int q = (int)(t * 256.0f);
    return q < 0 ? 0 : (q > 255 ? 255 : q);
}

// ws layout:
//   u32 aux[0]            : mode (0 = LDS block table, 1 = u8 gather, 2 = u16 gather)
//   u32 aux[1..1+NBMAX)   : block table (mode 0)
//   byte TAB_OFF=4352 ... : gather table (u8 mode 1 / u16 mode 2)
#define TAB_OFF 4352

__global__ __launch_bounds__(256) void btab_build_kernel(
    const float* __restrict__ times_in,
    const float* __restrict__ decay_rate,
    u32*         __restrict__ aux,
    int n_in)
{
    float d2[C_IN];
    decay_d2(decay_rate, d2);
    const int tid = threadIdx.x;
    if (!decay_uniform(d2, n_in)) {
        if (tid == 0) aux[0] = 2u;
        return;
    }
    __shared__ int ls_start[257];
    __shared__ int s_bad;
    if (tid == 0) s_bad = 0;
    if (tid < 256) {                   // first id with Fof(times_in[id]) >= q
        const int q = tid;
        int lo = 0, hi = n_in;
        while (lo < hi) {
            int mid = (lo + hi) >> 1;
            if (Fof(times_in[mid]) >= q) hi = mid; else lo = mid + 1;
        }
        ls_start[q] = lo;
    }
    __syncthreads();
    const int nb = (n_in + BSIZE - 1) >> BSHIFT;
    for (int i = tid; i < nb && i < NBMAX; i += blockDim.x) {
        const int s = i << BSHIFT;
        const int e = min(s + BSIZE, n_in) - 1;
        const int base = Fof(times_in[s]);
        const int endq = Fof(times_in[e]);
        u32 entry;
        if (endq == base) {
            entry = (u32)base | ((u32)BSIZE << 8);            // no breakpoint
        } else if (endq == base + 1) {
            entry = (u32)base | ((u32)(ls_start[base + 1] - s) << 8);
        } else {
            entry = 0; s_bad = 1;                             // multi-breakpoint
        }
        aux[1 + i] = entry;
    }
    __syncthreads();
    if (tid == 0) aux[0] = (nb <= NBMAX && !s_bad) ? 0u : 1u;
}

// Builds the per-id gather table ONLY when mode != 0 (early-exit otherwise).
__global__ __launch_bounds__(256) void fill_tab_kernel(
    const float* __restrict__ times_in,
    const int*   __restrict__ seg_ids,
    const u32*   __restrict__ aux,
    u8*          __restrict__ tab,
    int n_in)
{
    const u32 mode = aux[0];
    if (mode == 0u) return;
    int i = blockIdx.x * blockDim.x + threadIdx.x;
    int stride = gridDim.x * blockDim.x;
    if (mode == 1u) {
        for (; i < n_in; i += stride) {
            float t = times_in[i];
            unsigned q = (unsigned)(t * 256.0f);
            if (q > 255u) q = 255u;
            tab[i] = (u8)q;
        }
    } else {
        u16* t16 = (u16*)tab;
        for (; i < n_in; i += stride) {
            float t = times_in[i];
            unsigned q = (unsigned)(t * QS16);
            if (q > 16383u) q = 16383u;
            t16[i] = (u16)((q << 2) | ((unsigned)seg_ids[i] & 3u));
        }
    }
}

template<bool USE_TABLE>
__global__ __launch_bounds__(256, 3) void onehot_conv_kernel(
    const u8*    __restrict__ tab,
    const u32*   __restrict__ aux,
    const float* __restrict__ times_in,
    const int*   __restrict__ seg_ids,
    const float* __restrict__ times_out,
    const int*   __restrict__ pred_ids,      // (n_out, K, C_IN)
    const float* __restrict__ decay_rate,    // (C_IN,) uniform
    const float* __restrict__ kern,          // (K, C_IN, F)
    const float* __restrict__ bias,          // (F,)    uniform
    float*       __restrict__ out,           // (n_out, F)
    int n_in, int n_out)
{
    __shared__ float s_kern[TAPS * NF];      // 2304 B, broadcast reads
    __shared__ u32   s_btab[NBMAX];          // 4 KB block table (mode 0)

    const int tid = threadIdx.x;
    float d2[C_IN];
    decay_d2(decay_rate, d2);

    const u32 mode = USE_TABLE ? aux[0] : 2u;   // wave-uniform

    for (int i = tid; i < TAPS * NF; i += blockDim.x) s_kern[i] = kern[i];
    if (mode == 0u) {
        const int nb = (n_in + BSIZE - 1) >> BSHIFT;
        for (int i = tid; i < nb; i += blockDim.x) s_btab[i] = aux[1 + i];
    }
    __syncthreads();

    const int bid = blockIdx.x;
    const int nfb = n_out / OPB;             // full fast-path blocks

    if (mode == 0u) {
        const float D = d2[0];
        const float dscale = D * (1.0f / 256.0f);

        if (bid < nfb) {
            // ---- fast path: P=2 CONTIGUOUS outputs/thread, zero conditionals
            const int o0 = bid * OPB + tid * P;
            const float2v to2 = *reinterpret_cast<const float2v*>(times_out + o0);
            const float dbase0 = D * (0.5f / 256.0f) - D * to2[0];
            const float dbase1 = D * (0.5f / 256.0f) - D * to2[1];

            float acc0[NF], acc1[NF];
#pragma unroll
            for (int f = 0; f < NF; ++f) { acc0[f] = bias[f]; acc1[f] = bias[f]; }

            // 288 B contiguous per thread (two pred rows back-to-back)
            const int4v* pp = reinterpret_cast<const int4v*>(pred_ids + (size_t)o0 * TAPS);

#pragma unroll
            for (int q = 0; q < TAPS / 4; ++q) {
                const int4v a = pp[q];
                const int4v b = pp[q + TAPS / 4];
#pragma unroll
                for (int j = 0; j < 4; ++j) {
                    const int tap = q * 4 + j;

                    const int ida = a[j];
                    const bool va = (u32)ida < (u32)n_in;
                    const int ica = va ? ida : 0;
                    const u32 ea = s_btab[ica >> BSHIFT];
                    const u32 ua = (ea & 0xFFu) +
                        (((u32)(ica & (BSIZE - 1)) >= (ea >> 8)) ? 1u : 0u);
                    const float wa = va ? exp2f(fmaf((float)ua, dscale, dbase0)) : 0.0f;

                    const int idb = b[j];
                    const bool vb = (u32)idb < (u32)n_in;
                    const int icb = vb ? idb : 0;
                    const u32 eb = s_btab[icb >> BSHIFT];
                    const u32 ub = (eb & 0xFFu) +
                        (((u32)(icb & (BSIZE - 1)) >= (eb >> 8)) ? 1u : 0u);
                    const float wb = vb ? exp2f(fmaf((float)ub, dscale, dbase1)) : 0.0f;

                    const float4v* kr = reinterpret_cast<const float4v*>(&s_kern[tap * NF]);
#pragma unroll
                    for (int r = 0; r < 4; ++r) {
                        const float4v k4 = kr[r];   // one broadcast read, 8 FMAs
                        acc0[r*4+0] = fmaf(wa, k4.x, acc0[r*4+0]);
                        acc0[r*4+1] = fmaf(wa, k4.y, acc0[r*4+1]);
                        acc0[r*4+2] = fmaf(wa, k4.z, acc0[r*4+2]);
                        acc0[r*4+3] = fmaf(wa, k4.w, acc0[r*4+3]);
                        acc1[r*4+0] = fmaf(wb, k4.x, acc1[r*4+0]);
                        acc1[r*4+1] = fmaf(wb, k4.y, acc1[r*4+1]);
                        acc1[r*4+2] = fmaf(wb, k4.z, acc1[r*4+2]);
                        acc1[r*4+3] = fmaf(wb, k4.w, acc1[r*4+3]);
                    }
                }
            }

            // 128 B contiguous per thread
            float4v* op = reinterpret_cast<float4v*>(out + (size_t)o0 * NF);
#pragma unroll
            for (int r = 0; r < 4; ++r) {
                float4v v0 = { acc0[r*4+0], acc0[r*4+1], acc0[r*4+2], acc0[r*4+3] };
                op[r] = v0;
            }
#pragma unroll
            for (int r = 0; r < 4; ++r) {
                float4v v1 = { acc1[r*4+0], acc1[r*4+1], acc1[r*4+2], acc1[r*4+3] };
                op[4 + r] = v1;
            }
        } else {
            // ---- tail: single output per thread (round-7 proven path)
            const int o = nfb * OPB + (bid - nfb) * BLOCK + tid;
            if (o >= n_out) return;
            const float t_out = times_out[o];
            const float dbase = D * (0.5f / 256.0f) - D * t_out;

            float acc[NF];
#pragma unroll
            for (int f = 0; f < NF; ++f) acc[f] = bias[f];
            const int4v* pids = reinterpret_cast<const int4v*>(pred_ids + (size_t)o * TAPS);
#pragma unroll
            for (int q = 0; q < TAPS / 4; ++q) {
                const int4v a = pids[q];
#pragma unroll
                for (int j = 0; j < 4; ++j) {
                    const int tap = q * 4 + j;
                    const int id = a[j];
                    const bool valid = (u32)id < (u32)n_in;
                    const int idc = valid ? id : 0;
                    const u32 e = s_btab[idc >> BSHIFT];
                    const u32 uu = (e & 0xFFu) +
                        (((u32)(idc & (BSIZE - 1)) >= (e >> 8)) ? 1u : 0u);
                    const float w = valid ? exp2f(fmaf((float)uu, dscale, dbase)) : 0.0f;
                    const float4v* kr = reinterpret_cast<const float4v*>(&s_kern[tap * NF]);
#pragma unroll
                    for (int r = 0; r < 4; ++r) {
                        const float4v k4 = kr[r];
                        acc[r*4+0] = fmaf(w, k4.x, acc[r*4+0]);
                        acc[r*4+1] = fmaf(w, k4.y, acc[r*4+1]);
                        acc[r*4+2] = fmaf(w, k4.z, acc[r*4+2]);
                        acc[r*4+3] = fmaf(w, k4.w, acc[r*4+3]);
                    }
                }
            }
            float4v* op = reinterpret_cast<float4v*>(out + (size_t)o * NF);
#pragma unroll
            for (int r = 0; r < 4; ++r) {
                float4v v = { acc[r*4+0], acc[r*4+1], acc[r*4+2], acc[r*4+3] };
                op[r] = v;
            }
        }
        return;
    }

    // ---- cold paths (mode 1 / mode 2 / no-table): per-output sequential
    int obase, ocount;
    if (bid < nfb) { obase = bid * OPB + tid * P; ocount = P; }
    else { obase = nfb * OPB + (bid - nfb) * BLOCK + tid; ocount = 1; }

    for (int k = 0; k < ocount; ++k) {
        const int o = obase + k;
        if (o >= n_out) continue;
        const float t_out = times_out[o];
        float acc[NF];
#pragma unroll
        for (int f = 0; f < NF; ++f) acc[f] = bias[f];
        const int4v* pids = reinterpret_cast<const int4v*>(pred_ids + (size_t)o * TAPS);
        int4v vq[TAPS / 4];
#pragma unroll
        for (int q = 0; q < TAPS / 4; ++q) vq[q] = pids[q];

        if (mode == 1u) {
            const float D = d2[0];
            const float dscale = D * (1.0f / 256.0f);
            const float dbase  = D * (0.5f / 256.0f) - D * t_out;
            unsigned uu[TAPS];
#pragma unroll
            for (int tap = 0; tap < TAPS; ++tap) {
                const int id = vq[tap >> 2][tap & 3];
                const int p  = ((u32)id < (u32)n_in) ? id : (n_in - 1);
                uu[tap] = tab[p];
            }
#pragma unroll
            for (int tap = 0; tap < TAPS; ++tap) {
                const int id = vq[tap >> 2][tap & 3];
                const bool valid = (u32)id < (u32)n_in;
                const float w = valid ? exp2f(fmaf((float)uu[tap], dscale, dbase)) : 0.0f;
                const float4v* kr = reinterpret_cast<const float4v*>(&s_kern[tap * NF]);
#pragma unroll
                for (int r = 0; r < 4; ++r) {
                    float4v k4 = kr[r];
                    acc[r*4+0] = fmaf(w, k4.x, acc[r*4+0]);
                    acc[r*4+1] = fmaf(w, k4.y, acc[r*4+1]);
                    acc[r*4+2] = fmaf(w, k4.z, acc[r*4+2]);
                    acc[r*4+3] = fmaf(w, k4.w, acc[r*4+3]);
                }
            }
        } else {
            const u16* t16 = (const u16*)tab;
            unsigned uu[TAPS];
#pragma unroll
            for (int tap = 0; tap < TAPS; ++tap) {
                const int id = vq[tap >> 2][tap & 3];
                const int p  = ((u32)id < (u32)n_in) ? id : (n_in - 1);
                if (USE_TABLE) {
                    uu[tap] = t16[p];
                } else {
                    float t = times_in[p];
                    unsigned q = (unsigned)(t * QS16);
                    if (q > 16383u) q = 16383u;
                    uu[tap] = (q << 2) | ((unsigned)seg_ids[p] & 3u);
                }
            }
#pragma unroll
            for (int tap = 0; tap < TAPS; ++tap) {
                const int id = vq[tap >> 2][tap & 3];
                const bool valid = (u32)id < (u32)n_in;
                const unsigned u = uu[tap];
                const int c = (int)(u & 3u);
                const float t = (float)(u >> 2) * (1.0f / QS16) + (0.5f / QS16);
                const float dd = (c & 2) ? ((c & 1) ? d2[3] : d2[2])
                                         : ((c & 1) ? d2[1] : d2[0]);
                const float w = valid ? exp2f(-dd * (t_out - t)) : 0.0f;
                const float4v* kr = reinterpret_cast<const float4v*>(&s_kern[tap * NF]);
#pragma unroll
                for (int r = 0; r < 4; ++r) {
                    float4v k4 = kr[r];
                    acc[r*4+0] = fmaf(w, k4.x, acc[r*4+0]);
                    acc[r*4+1] = fmaf(w, k4.y, acc[r*4+1]);
                    acc[r*4+2] = fmaf(w, k4.z, acc[r*4+2]);
                    acc[r*4+3] = fmaf(w, k4.w, acc[r*4+3]);
                }
            }
        }
        float4v* op = reinterpret_cast<float4v*>(out + (size_t)o * NF);
#pragma unroll
        for (int r = 0; r < 4; ++r) {
            float4v v = { acc[r*4+0], acc[r*4+1], acc[r*4+2], acc[r*4+3] };
            op[r] = v;
        }
    }
}

extern "C" void kernel_launch(void* const* d_in, const int* in_sizes, int n_in_arrs,
                              void* d_out, int out_size, void* d_ws, size_t ws_size,
                              hipStream_t stream) {
    (void)n_in_arrs; (void)out_size;
    const float* times_in   = (const float*)d_in[0];
    const float* times_out  = (const float*)d_in[1];
    const int*   seg_ids    = (const int*)d_in[2];
    const int*   pred_ids   = (const int*)d_in[3];
    const float* decay_rate = (const float*)d_in[4];
    const float* kern       = (const float*)d_in[5];
    const float* bias       = (const float*)d_in[6];

    const int n_in  = in_sizes[0];
    const int n_out = in_sizes[1];

    float* out = (float*)d_out;

    const int nfb  = n_out / OPB;
    const int tail = n_out - nfb * OPB;
    const int grid = nfb + (tail + BLOCK - 1) / BLOCK;

    const size_t need = (size_t)TAB_OFF + (size_t)n_in * 2;

    if (ws_size >= need) {
        u32* aux = (u32*)d_ws;
        u8*  tab = (u8*)d_ws + TAB_OFF;
        btab_build_kernel<<<1, 256, 0, stream>>>(times_in, decay_rate, aux, n_in);
        fill_tab_kernel<<<256, 256, 0, stream>>>(times_in, seg_ids, aux, tab, n_in);
        onehot_conv_kernel<true><<<grid, BLOCK, 0, stream>>>(
            tab, aux, times_in, seg_ids, times_out, pred_ids,
            decay_rate, kern, bias, out, n_in, n_out);
    } else {
        onehot_conv_kernel<false><<<grid, BLOCK, 0, stream>>>(
            nullptr, nullptr, times_in, seg_ids, times_out, pred_ids,
            decay_rate, kern, bias, out, n_in, n_out);
    }
}

// Round 10
// 747.284 us; speedup vs baseline: 1.3214x; 1.0017x over previous
//
#include <hip/hip_runtime.h>

#define C_IN 4
#define NF 16
#define TAPS 36               // K * C_IN
#define QS16 16384.0f         // u16 general-path time quantization
#define BSHIFT 11             // 2048 ids per block-table entry
#define BSIZE 2048
#define NBMAX 1024            // supports n_in <= 2^21
#define BLOCK 256
#define PF 2                  // outputs per thread in conv_fast
#define OPB (PF * BLOCK)      // 512 outputs per fast block
#define TAB_OFF 4352          // byte offset of gather table in ws

typedef int   int4v   __attribute__((ext_vector_type(4)));
typedef float float4v __attribute__((ext_vector_type(4)));
typedef unsigned short u16;
typedef unsigned char  u8;
typedef unsigned int   u32;

// softplus(x)*log2(e), stable — identical in all kernels (mode consistency)
__device__ __forceinline__ float softplus_log2e(float x) {
    return (fmaxf(x, 0.0f) + log1pf(expf(-fabsf(x)))) * 1.4426950408889634f;
}
__device__ __forceinline__ void decay_d2(const float* __restrict__ dr, float* d2) {
#pragma unroll
    for (int c = 0; c < C_IN; ++c) d2[c] = softplus_log2e(dr[c]);
}
__device__ __forceinline__ bool decay_uniform(const float* d2, int n_in) {
    return (d2[0] == d2[1]) & (d2[1] == d2[2]) & (d2[2] == d2[3]) &
           (d2[0] <= 2.0f) & (n_in >= 2);
}
__device__ __forceinline__ int Fof(float t) {   // floor(256*t), clamped
    int q = (int)(t * 256.0f);
    return q < 0 ? 0 : (q > 255 ? 255 : q);
}

// ws layout:
//   u32 aux[0]            : mode (0 = LDS block table, 1 = u8 gather, 2 = u16 gather)
//   u32 aux[1..1+NBMAX)   : block table (mode 0)
//   byte TAB_OFF ...      : gather table (u8 mode 1 / u16 mode 2)

__global__ __launch_bounds__(256) void btab_build_kernel(
    const float* __restrict__ times_in,
    const float* __restrict__ decay_rate,
    u32*         __restrict__ aux,
    int n_in)
{
    float d2[C_IN];
    decay_d2(decay_rate, d2);
    const int tid = threadIdx.x;
    if (!decay_uniform(d2, n_in)) {
        if (tid == 0) aux[0] = 2u;
        return;
    }
    __shared__ int ls_start[257];
    __shared__ int s_bad;
    if (tid == 0) s_bad = 0;
    if (tid < 256) {                   // first id with Fof(times_in[id]) >= q
        const int q = tid;
        int lo = 0, hi = n_in;
        while (lo < hi) {
            int mid = (lo + hi) >> 1;
            if (Fof(times_in[mid]) >= q) hi = mid; else lo = mid + 1;
        }
        ls_start[q] = lo;
    }
    __syncthreads();
    const int nb = (n_in + BSIZE - 1) >> BSHIFT;
    for (int i = tid; i < nb && i < NBMAX; i += blockDim.x) {
        const int s = i << BSHIFT;
        const int e = min(s + BSIZE, n_in) - 1;
        const int base = Fof(times_in[s]);
        const int endq = Fof(times_in[e]);
        u32 entry;
        if (endq == base) {
            entry = (u32)base | ((u32)BSIZE << 8);            // no breakpoint
        } else if (endq == base + 1) {
            entry = (u32)base | ((u32)(ls_start[base + 1] - s) << 8);
        } else {
            entry = 0; s_bad = 1;                             // multi-breakpoint
        }
        aux[1 + i] = entry;
    }
    __syncthreads();
    if (tid == 0) aux[0] = (nb <= NBMAX && !s_bad) ? 0u : 1u;
}

// Builds the per-id gather table ONLY when mode != 0 (early-exit otherwise).
__global__ __launch_bounds__(256) void fill_tab_kernel(
    const float* __restrict__ times_in,
    const int*   __restrict__ seg_ids,
    const u32*   __restrict__ aux,
    u8*          __restrict__ tab,
    int n_in)
{
    const u32 mode = aux[0];
    if (mode == 0u) return;
    int i = blockIdx.x * blockDim.x + threadIdx.x;
    int stride = gridDim.x * blockDim.x;
    if (mode == 1u) {
        for (; i < n_in; i += stride) {
            float t = times_in[i];
            unsigned q = (unsigned)(t * 256.0f);
            if (q > 255u) q = 255u;
            tab[i] = (u8)q;
        }
    } else {
        u16* t16 = (u16*)tab;
        for (; i < n_in; i += stride) {
            float t = times_in[i];
            unsigned q = (unsigned)(t * QS16);
            if (q > 16383u) q = 16383u;
            t16[i] = (u16)((q << 2) | ((unsigned)seg_ids[i] & 3u));
        }
    }
}

// ---- FAST kernel: mode 0 ONLY. One path, fully unrolled, branch-free body.
__global__ __launch_bounds__(256, 3) void conv_fast_kernel(
    const u32*   __restrict__ aux,
    const float* __restrict__ times_out,
    const int*   __restrict__ pred_ids,      // (n_out, K, C_IN)
    const float* __restrict__ decay_rate,
    const float* __restrict__ kern,          // (K, C_IN, F)
    const float* __restrict__ bias,          // (F,)
    float*       __restrict__ out,           // (n_out, F)
    int n_in, int n_out)
{
    if (aux[0] != 0u) return;                 // not our mode (wave-uniform)

    __shared__ float s_kern[TAPS * NF];       // 2304 B, broadcast reads
    __shared__ u32   s_btab[NBMAX];           // 4 KB block table

    const int tid = threadIdx.x;
    for (int i = tid; i < TAPS * NF; i += BLOCK) s_kern[i] = kern[i];
    {
        const int nb = (n_in + BSIZE - 1) >> BSHIFT;
        for (int i = tid; i < nb; i += BLOCK) s_btab[i] = aux[1 + i];
    }
    __syncthreads();

    const float D = softplus_log2e(decay_rate[0]);   // mode 0 => uniform decay
    const float dscale = D * (1.0f / 256.0f);
    const float half_t = D * (0.5f / 256.0f);

    if (n_out < 2) {                          // degenerate corner, never hot
        if (blockIdx.x == 0 && tid == 0 && n_out == 1) {
            const float dbase = half_t - D * times_out[0];
            float acc[NF];
            for (int f = 0; f < NF; ++f) acc[f] = bias[f];
            for (int tap = 0; tap < TAPS; ++tap) {
                const int id = pred_ids[tap];
                const bool valid = (u32)id < (u32)n_in;
                const int idc = valid ? id : 0;
                const u32 e = s_btab[idc >> BSHIFT];
                const u32 uu = (e & 0xFFu) +
                    (((u32)(idc & (BSIZE - 1)) >= (e >> 8)) ? 1u : 0u);
                const float w = valid ? exp2f(fmaf((float)uu, dscale, dbase)) : 0.0f;
                for (int f = 0; f < NF; ++f) acc[f] = fmaf(w, s_kern[tap*NF+f], acc[f]);
            }
            for (int f = 0; f < NF; ++f) out[f] = acc[f];
        }
        return;
    }

    // P=2 contiguous outputs/thread; tail handled by clamping: duplicate
    // threads recompute identical values -> benign, deterministic writes.
    int o0 = blockIdx.x * OPB + tid * PF;
    if (o0 > n_out - 2) o0 = n_out - 2;

    const float dbase0 = half_t - D * times_out[o0];
    const float dbase1 = half_t - D * times_out[o0 + 1];

    float acc0[NF], acc1[NF];
#pragma unroll
    for (int f = 0; f < NF; ++f) { const float b = bias[f]; acc0[f] = b; acc1[f] = b; }

    // 288 B contiguous per thread (two pred rows back-to-back), 16B-aligned
    const int4v* pp = reinterpret_cast<const int4v*>(pred_ids + (size_t)o0 * TAPS);

#pragma unroll
    for (int q = 0; q < TAPS / 4; ++q) {
        const int4v a = pp[q];
        const int4v b = pp[q + TAPS / 4];
#pragma unroll
        for (int j = 0; j < 4; ++j) {
            const int tap = q * 4 + j;

            const int ida = a[j];
            const bool va = (u32)ida < (u32)n_in;
            const int ica = va ? ida : 0;
            const u32 ea = s_btab[ica >> BSHIFT];
            const u32 ua = (ea & 0xFFu) +
                (((u32)(ica & (BSIZE - 1)) >= (ea >> 8)) ? 1u : 0u);
            const float wa = va ? exp2f(fmaf((float)ua, dscale, dbase0)) : 0.0f;

            const int idb = b[j];
            const bool vb = (u32)idb < (u32)n_in;
            const int icb = vb ? idb : 0;
            const u32 eb = s_btab[icb >> BSHIFT];
            const u32 ub = (eb & 0xFFu) +
                (((u32)(icb & (BSIZE - 1)) >= (eb >> 8)) ? 1u : 0u);
            const float wb = vb ? exp2f(fmaf((float)ub, dscale, dbase1)) : 0.0f;

            const float4v* kr = reinterpret_cast<const float4v*>(&s_kern[tap * NF]);
#pragma unroll
            for (int r = 0; r < 4; ++r) {
                const float4v k4 = kr[r];       // one broadcast b128 read, 8 FMAs
                acc0[r*4+0] = fmaf(wa, k4.x, acc0[r*4+0]);
                acc0[r*4+1] = fmaf(wa, k4.y, acc0[r*4+1]);
                acc0[r*4+2] = fmaf(wa, k4.z, acc0[r*4+2]);
                acc0[r*4+3] = fmaf(wa, k4.w, acc0[r*4+3]);
                acc1[r*4+0] = fmaf(wb, k4.x, acc1[r*4+0]);
                acc1[r*4+1] = fmaf(wb, k4.y, acc1[r*4+1]);
                acc1[r*4+2] = fmaf(wb, k4.z, acc1[r*4+2]);
                acc1[r*4+3] = fmaf(wb, k4.w, acc1[r*4+3]);
            }
        }
    }

    // 128 B contiguous per thread; each 64 B output row fully written -> no RMW
    float4v* op = reinterpret_cast<float4v*>(out + (size_t)o0 * NF);
#pragma unroll
    for (int r = 0; r < 4; ++r) {
        float4v v = { acc0[r*4+0], acc0[r*4+1], acc0[r*4+2], acc0[r*4+3] };
        op[r] = v;
    }
#pragma unroll
    for (int r = 0; r < 4; ++r) {
        float4v v = { acc1[r*4+0], acc1[r*4+1], acc1[r*4+2], acc1[r*4+3] };
        op[4 + r] = v;
    }
}

// ---- GATHER kernel: modes 1/2 (and no-ws fallback). Round-5 proven codegen.
template<bool USE_TABLE>
__global__ __launch_bounds__(256, 4) void conv_gather_kernel(
    const u8*    __restrict__ tab,
    const u32*   __restrict__ aux,
    const float* __restrict__ times_in,
    const int*   __restrict__ seg_ids,
    const float* __restrict__ times_out,
    const int*   __restrict__ pred_ids,
    const float* __restrict__ decay_rate,
    const float* __restrict__ kern,
    const float* __restrict__ bias,
    float*       __restrict__ out,
    int n_in, int n_out)
{
    const u32 mode = USE_TABLE ? aux[0] : 2u;
    if (USE_TABLE && mode == 0u) return;     // fast kernel owns mode 0

    __shared__ float s_kern[TAPS * NF];
    const int tid = threadIdx.x;
    for (int i = tid; i < TAPS * NF; i += blockDim.x) s_kern[i] = kern[i];
    __syncthreads();

    float d2[C_IN];
    decay_d2(decay_rate, d2);

    const int o = blockIdx.x * blockDim.x + tid;
    if (o >= n_out) return;

    const float t_out = times_out[o];

    float acc[NF];
#pragma unroll
    for (int f = 0; f < NF; ++f) acc[f] = bias[f];

    const int4v* pids = reinterpret_cast<const int4v*>(pred_ids + (size_t)o * TAPS);
    int4v vq[TAPS / 4];
#pragma unroll
    for (int q = 0; q < TAPS / 4; ++q) vq[q] = pids[q];

    if (mode == 1u) {
        // u8 path (uniform decay, table too big for one L2? still L2-friendly)
        const float D = d2[0];
        const float dscale = D * (1.0f / 256.0f);
        const float dbase  = D * (0.5f / 256.0f) - D * t_out;
        unsigned uu[TAPS];
#pragma unroll
        for (int tap = 0; tap < TAPS; ++tap) {
            const int id = vq[tap >> 2][tap & 3];
            const int p  = ((u32)id < (u32)n_in) ? id : (n_in - 1);
            uu[tap] = tab[p];
        }
#pragma unroll
        for (int tap = 0; tap < TAPS; ++tap) {
            const int id = vq[tap >> 2][tap & 3];
            const bool valid = (u32)id < (u32)n_in;
            const float w = valid ? exp2f(fmaf((float)uu[tap], dscale, dbase)) : 0.0f;
            const float4v* kr = reinterpret_cast<const float4v*>(&s_kern[tap * NF]);
#pragma unroll
            for (int r = 0; r < 4; ++r) {
                float4v k4 = kr[r];
                acc[r*4+0] = fmaf(w, k4.x, acc[r*4+0]);
                acc[r*4+1] = fmaf(w, k4.y, acc[r*4+1]);
                acc[r*4+2] = fmaf(w, k4.z, acc[r*4+2]);
                acc[r*4+3] = fmaf(w, k4.w, acc[r*4+3]);
            }
        }
    } else {
        // u16 path (general decay) / direct-compute no-table fallback
        const u16* t16 = (const u16*)tab;
        unsigned uu[TAPS];
#pragma unroll
        for (int tap = 0; tap < TAPS; ++tap) {
            const int id = vq[tap >> 2][tap & 3];
            const int p  = ((u32)id < (u32)n_in) ? id : (n_in - 1);
            if (USE_TABLE) {
                uu[tap] = t16[p];
            } else {
                float t = times_in[p];
                unsigned q = (unsigned)(t * QS16);
                if (q > 16383u) q = 16383u;
                uu[tap] = (q << 2) | ((unsigned)seg_ids[p] & 3u);
            }
        }
#pragma unroll
        for (int tap = 0; tap < TAPS; ++tap) {
            const int id = vq[tap >> 2][tap & 3];
            const bool valid = (u32)id < (u32)n_in;
            const unsigned u = uu[tap];
            const int c = (int)(u & 3u);
            const float t = (float)(u >> 2) * (1.0f / QS16) + (0.5f / QS16);
            const float dd = (c & 2) ? ((c & 1) ? d2[3] : d2[2])
                                     : ((c & 1) ? d2[1] : d2[0]);
            const float w = valid ? exp2f(-dd * (t_out - t)) : 0.0f;
            const float4v* kr = reinterpret_cast<const float4v*>(&s_kern[tap * NF]);
#pragma unroll
            for (int r = 0; r < 4; ++r) {
                float4v k4 = kr[r];
                acc[r*4+0] = fmaf(w, k4.x, acc[r*4+0]);
                acc[r*4+1] = fmaf(w, k4.y, acc[r*4+1]);
                acc[r*4+2] = fmaf(w, k4.z, acc[r*4+2]);
                acc[r*4+3] = fmaf(w, k4.w, acc[r*4+3]);
            }
        }
    }

    float4v* op = reinterpret_cast<float4v*>(out + (size_t)o * NF);
#pragma unroll
    for (int q = 0; q < 4; ++q) {
        float4v r = { acc[q*4+0], acc[q*4+1], acc[q*4+2], acc[q*4+3] };
        op[q] = r;
    }
}

extern "C" void kernel_launch(void* const* d_in, const int* in_sizes, int n_in_arrs,
                              void* d_out, int out_size, void* d_ws, size_t ws_size,
                              hipStream_t stream) {
    (void)n_in_arrs; (void)out_size;
    const float* times_in   = (const float*)d_in[0];
    const float* times_out  = (const float*)d_in[1];
    const int*   seg_ids    = (const int*)d_in[2];
    const int*   pred_ids   = (const int*)d_in[3];
    const float* decay_rate = (const float*)d_in[4];
    const float* kern       = (const float*)d_in[5];
    const float* bias       = (const float*)d_in[6];

    const int n_in  = in_sizes[0];
    const int n_out = in_sizes[1];

    float* out = (float*)d_out;

    const size_t need = (size_t)TAB_OFF + (size_t)n_in * 2;
    const int grid_g  = (n_out + BLOCK - 1) / BLOCK;

    if (ws_size >= need) {
        u32* aux = (u32*)d_ws;
        u8*  tab = (u8*)d_ws + TAB_OFF;
        btab_build_kernel<<<1, 256, 0, stream>>>(times_in, decay_rate, aux, n_in);
        fill_tab_kernel<<<256, 256, 0, stream>>>(times_in, seg_ids, aux, tab, n_in);
        if (n_out > 0) {
            const int grid_f = (n_out + OPB - 1) / OPB;
            conv_fast_kernel<<<grid_f, BLOCK, 0, stream>>>(
                aux, times_out, pred_ids, decay_rate, kern, bias, out, n_in, n_out);
            conv_gather_kernel<true><<<grid_g, BLOCK, 0, stream>>>(
                tab, aux, times_in, seg_ids, times_out, pred_ids,
                decay_rate, kern, bias, out, n_in, n_out);
        }
    } else if (n_out > 0) {
        conv_gather_kernel<false><<<grid_g, BLOCK, 0, stream>>>(
            nullptr, nullptr, times_in, seg_ids, times_out, pred_ids,
            decay_rate, kern, bias, out, n_in, n_out);
    }
}

// Round 11
// 69.577 us; speedup vs baseline: 14.1920x; 10.7404x over previous
//
#include <hip/hip_runtime.h>

#define C_IN 4
#define NF 16
#define TAPS 36               // K * C_IN
#define QS16 16384.0f         // u16 general-path time quantization
#define BSHIFT 11             // 2048 ids per block-table entry
#define BSIZE 2048
#define NBMAX 1024            // supports n_in <= 2^21
#define BLOCK 256
#define TAB_OFF 4352          // byte offset of gather table in ws

typedef int   int4v   __attribute__((ext_vector_type(4)));
typedef float float4v __attribute__((ext_vector_type(4)));
typedef unsigned short u16;
typedef unsigned char  u8;
typedef unsigned int   u32;

// softplus(x)*log2(e), stable — identical in all kernels (mode consistency)
__device__ __forceinline__ float softplus_log2e(float x) {
    return (fmaxf(x, 0.0f) + log1pf(expf(-fabsf(x)))) * 1.4426950408889634f;
}
__device__ __forceinline__ void decay_d2(const float* __restrict__ dr, float* d2) {
#pragma unroll
    for (int c = 0; c < C_IN; ++c) d2[c] = softplus_log2e(dr[c]);
}
__device__ __forceinline__ bool decay_uniform(const float* d2, int n_in) {
    return (d2[0] == d2[1]) & (d2[1] == d2[2]) & (d2[2] == d2[3]) &
           (d2[0] <= 2.0f) & (n_in >= 2);
}
__device__ __forceinline__ int Fof(float t) {   // floor(256*t), clamped
    int q = (int)(t * 256.0f);
    return q < 0 ? 0 : (q > 255 ? 255 : q);
}

// ws layout:
//   u32 aux[0]            : mode (0 = LDS block table, 1 = u8 gather, 2 = u16 gather)
//   u32 aux[1..1+NBMAX)   : block table (mode 0)
//   byte TAB_OFF ...      : gather table (u8 mode 1 / u16 mode 2)

__global__ __launch_bounds__(256) void btab_build_kernel(
    const float* __restrict__ times_in,
    const float* __restrict__ decay_rate,
    u32*         __restrict__ aux,
    int n_in)
{
    float d2[C_IN];
    decay_d2(decay_rate, d2);
    const int tid = threadIdx.x;
    if (!decay_uniform(d2, n_in)) {
        if (tid == 0) aux[0] = 2u;
        return;
    }
    __shared__ int ls_start[257];
    __shared__ int s_bad;
    if (tid == 0) s_bad = 0;
    if (tid < 256) {                   // first id with Fof(times_in[id]) >= q
        const int q = tid;
        int lo = 0, hi = n_in;
        while (lo < hi) {
            int mid = (lo + hi) >> 1;
            if (Fof(times_in[mid]) >= q) hi = mid; else lo = mid + 1;
        }
        ls_start[q] = lo;
    }
    __syncthreads();
    const int nb = (n_in + BSIZE - 1) >> BSHIFT;
    for (int i = tid; i < nb && i < NBMAX; i += blockDim.x) {
        const int s = i << BSHIFT;
        const int e = min(s + BSIZE, n_in) - 1;
        const int base = Fof(times_in[s]);
        const int endq = Fof(times_in[e]);
        u32 entry;
        if (endq == base) {
            entry = (u32)base | ((u32)BSIZE << 8);            // no breakpoint
        } else if (endq == base + 1) {
            entry = (u32)base | ((u32)(ls_start[base + 1] - s) << 8);
        } else {
            entry = 0; s_bad = 1;                             // multi-breakpoint
        }
        aux[1 + i] = entry;
    }
    __syncthreads();
    if (tid == 0) aux[0] = (nb <= NBMAX && !s_bad) ? 0u : 1u;
}

// Builds the per-id gather table ONLY when mode != 0 (early-exit otherwise).
__global__ __launch_bounds__(256) void fill_tab_kernel(
    const float* __restrict__ times_in,
    const int*   __restrict__ seg_ids,
    const u32*   __restrict__ aux,
    u8*          __restrict__ tab,
    int n_in)
{
    const u32 mode = aux[0];
    if (mode == 0u) return;
    int i = blockIdx.x * blockDim.x + threadIdx.x;
    int stride = gridDim.x * blockDim.x;
    if (mode == 1u) {
        for (; i < n_in; i += stride) {
            float t = times_in[i];
            unsigned q = (unsigned)(t * 256.0f);
            if (q > 255u) q = 255u;
            tab[i] = (u8)q;
        }
    } else {
        u16* t16 = (u16*)tab;
        for (; i < n_in; i += stride) {
            float t = times_in[i];
            unsigned q = (unsigned)(t * QS16);
            if (q > 16383u) q = 16383u;
            t16[i] = (u16)((q << 2) | ((unsigned)seg_ids[i] & 3u));
        }
    }
}

// ---- FAST kernel: mode 0 ONLY. Round-7 proven P=1 body (VGPR 64, no spills):
// batch all 36 LDS btab lookups into uu[36], then pure-VALU compute phase.
__global__ __launch_bounds__(256, 4) void conv_fast_kernel(
    const u32*   __restrict__ aux,
    const float* __restrict__ times_out,
    const int*   __restrict__ pred_ids,      // (n_out, K, C_IN)
    const float* __restrict__ decay_rate,
    const float* __restrict__ kern,          // (K, C_IN, F)
    const float* __restrict__ bias,          // (F,)
    float*       __restrict__ out,           // (n_out, F)
    int n_in, int n_out)
{
    if (aux[0] != 0u) return;                 // not our mode (wave-uniform)

    __shared__ float s_kern[TAPS * NF];       // 2304 B, broadcast reads
    __shared__ u32   s_btab[NBMAX];           // 4 KB block table

    const int tid = threadIdx.x;
    for (int i = tid; i < TAPS * NF; i += BLOCK) s_kern[i] = kern[i];
    {
        const int nb = (n_in + BSIZE - 1) >> BSHIFT;
        for (int i = tid; i < nb; i += BLOCK) s_btab[i] = aux[1 + i];
    }
    __syncthreads();

    const int o = blockIdx.x * BLOCK + tid;
    if (o >= n_out) return;

    const float D = softplus_log2e(decay_rate[0]);   // mode 0 => uniform decay
    const float dscale = D * (1.0f / 256.0f);
    const float t_out  = times_out[o];
    const float dbase  = D * (0.5f / 256.0f) - D * t_out;

    float acc[NF];
#pragma unroll
    for (int f = 0; f < NF; ++f) acc[f] = bias[f];

    // 144 B contiguous ids per thread, plain (L2-merged) loads
    const int4v* pids = reinterpret_cast<const int4v*>(pred_ids + (size_t)o * TAPS);
    int4v vq[TAPS / 4];
#pragma unroll
    for (int q = 0; q < TAPS / 4; ++q) vq[q] = pids[q];

    // phase 1: all 36 block-table lookups (LDS pipelined)
    unsigned uu[TAPS];
#pragma unroll
    for (int tap = 0; tap < TAPS; ++tap) {
        const int id  = vq[tap >> 2][tap & 3];
        const int idc = ((u32)id < (u32)n_in) ? id : 0;
        const u32 e = s_btab[idc >> BSHIFT];
        uu[tap] = (e & 0xFFu) + (((u32)(idc & (BSIZE - 1)) >= (e >> 8)) ? 1u : 0u);
    }

    // phase 2: weights + FMA against LDS-broadcast kernel rows
#pragma unroll
    for (int tap = 0; tap < TAPS; ++tap) {
        const int id = vq[tap >> 2][tap & 3];
        const bool valid = (u32)id < (u32)n_in;
        const float w = valid ? exp2f(fmaf((float)uu[tap], dscale, dbase)) : 0.0f;
        const float4v* kr = reinterpret_cast<const float4v*>(&s_kern[tap * NF]);
#pragma unroll
        for (int r = 0; r < 4; ++r) {
            const float4v k4 = kr[r];
            acc[r*4+0] = fmaf(w, k4.x, acc[r*4+0]);
            acc[r*4+1] = fmaf(w, k4.y, acc[r*4+1]);
            acc[r*4+2] = fmaf(w, k4.z, acc[r*4+2]);
            acc[r*4+3] = fmaf(w, k4.w, acc[r*4+3]);
        }
    }

    // plain stores: L2 merges 4x16B per line into full-line writebacks
    float4v* op = reinterpret_cast<float4v*>(out + (size_t)o * NF);
#pragma unroll
    for (int q = 0; q < 4; ++q) {
        float4v r = { acc[q*4+0], acc[q*4+1], acc[q*4+2], acc[q*4+3] };
        op[q] = r;
    }
}

// ---- GATHER kernel: modes 1/2 (and no-ws fallback). Round-5 proven codegen.
template<bool USE_TABLE>
__global__ __launch_bounds__(256, 4) void conv_gather_kernel(
    const u8*    __restrict__ tab,
    const u32*   __restrict__ aux,
    const float* __restrict__ times_in,
    const int*   __restrict__ seg_ids,
    const float* __restrict__ times_out,
    const int*   __restrict__ pred_ids,
    const float* __restrict__ decay_rate,
    const float* __restrict__ kern,
    const float* __restrict__ bias,
    float*       __restrict__ out,
    int n_in, int n_out)
{
    const u32 mode = USE_TABLE ? aux[0] : 2u;
    if (USE_TABLE && mode == 0u) return;     // fast kernel owns mode 0

    __shared__ float s_kern[TAPS * NF];
    const int tid = threadIdx.x;
    for (int i = tid; i < TAPS * NF; i += blockDim.x) s_kern[i] = kern[i];
    __syncthreads();

    float d2[C_IN];
    decay_d2(decay_rate, d2);

    const int o = blockIdx.x * blockDim.x + tid;
    if (o >= n_out) return;

    const float t_out = times_out[o];

    float acc[NF];
#pragma unroll
    for (int f = 0; f < NF; ++f) acc[f] = bias[f];

    const int4v* pids = reinterpret_cast<const int4v*>(pred_ids + (size_t)o * TAPS);
    int4v vq[TAPS / 4];
#pragma unroll
    for (int q = 0; q < TAPS / 4; ++q) vq[q] = pids[q];

    if (mode == 1u) {
        const float D = d2[0];
        const float dscale = D * (1.0f / 256.0f);
        const float dbase  = D * (0.5f / 256.0f) - D * t_out;
        unsigned uu[TAPS];
#pragma unroll
        for (int tap = 0; tap < TAPS; ++tap) {
            const int id = vq[tap >> 2][tap & 3];
            const int p  = ((u32)id < (u32)n_in) ? id : (n_in - 1);
            uu[tap] = tab[p];
        }
#pragma unroll
        for (int tap = 0; tap < TAPS; ++tap) {
            const int id = vq[tap >> 2][tap & 3];
            const bool valid = (u32)id < (u32)n_in;
            const float w = valid ? exp2f(fmaf((float)uu[tap], dscale, dbase)) : 0.0f;
            const float4v* kr = reinterpret_cast<const float4v*>(&s_kern[tap * NF]);
#pragma unroll
            for (int r = 0; r < 4; ++r) {
                float4v k4 = kr[r];
                acc[r*4+0] = fmaf(w, k4.x, acc[r*4+0]);
                acc[r*4+1] = fmaf(w, k4.y, acc[r*4+1]);
                acc[r*4+2] = fmaf(w, k4.z, acc[r*4+2]);
                acc[r*4+3] = fmaf(w, k4.w, acc[r*4+3]);
            }
        }
    } else {
        const u16* t16 = (const u16*)tab;
        unsigned uu[TAPS];
#pragma unroll
        for (int tap = 0; tap < TAPS; ++tap) {
            const int id = vq[tap >> 2][tap & 3];
            const int p  = ((u32)id < (u32)n_in) ? id : (n_in - 1);
            if (USE_TABLE) {
                uu[tap] = t16[p];
            } else {
                float t = times_in[p];
                unsigned q = (unsigned)(t * QS16);
                if (q > 16383u) q = 16383u;
                uu[tap] = (q << 2) | ((unsigned)seg_ids[p] & 3u);
            }
        }
#pragma unroll
        for (int tap = 0; tap < TAPS; ++tap) {
            const int id = vq[tap >> 2][tap & 3];
            const bool valid = (u32)id < (u32)n_in;
            const unsigned u = uu[tap];
            const int c = (int)(u & 3u);
            const float t = (float)(u >> 2) * (1.0f / QS16) + (0.5f / QS16);
            const float dd = (c & 2) ? ((c & 1) ? d2[3] : d2[2])
                                     : ((c & 1) ? d2[1] : d2[0]);
            const float w = valid ? exp2f(-dd * (t_out - t)) : 0.0f;
            const float4v* kr = reinterpret_cast<const float4v*>(&s_kern[tap * NF]);
#pragma unroll
            for (int r = 0; r < 4; ++r) {
                float4v k4 = kr[r];
                acc[r*4+0] = fmaf(w, k4.x, acc[r*4+0]);
                acc[r*4+1] = fmaf(w, k4.y, acc[r*4+1]);
                acc[r*4+2] = fmaf(w, k4.z, acc[r*4+2]);
                acc[r*4+3] = fmaf(w, k4.w, acc[r*4+3]);
            }
        }
    }

    float4v* op = reinterpret_cast<float4v*>(out + (size_t)o * NF);
#pragma unroll
    for (int q = 0; q < 4; ++q) {
        float4v r = { acc[q*4+0], acc[q*4+1], acc[q*4+2], acc[q*4+3] };
        op[q] = r;
    }
}

extern "C" void kernel_launch(void* const* d_in, const int* in_sizes, int n_in_arrs,
                              void* d_out, int out_size, void* d_ws, size_t ws_size,
                              hipStream_t stream) {
    (void)n_in_arrs; (void)out_size;
    const float* times_in   = (const float*)d_in[0];
    const float* times_out  = (const float*)d_in[1];
    const int*   seg_ids    = (const int*)d_in[2];
    const int*   pred_ids   = (const int*)d_in[3];
    const float* decay_rate = (const float*)d_in[4];
    const float* kern       = (const float*)d_in[5];
    const float* bias       = (const float*)d_in[6];

    const int n_in  = in_sizes[0];
    const int n_out = in_sizes[1];

    float* out = (float*)d_out;

    const size_t need = (size_t)TAB_OFF + (size_t)n_in * 2;
    const int grid = (n_out + BLOCK - 1) / BLOCK;

    if (ws_size >= need) {
        u32* aux = (u32*)d_ws;
        u8*  tab = (u8*)d_ws + TAB_OFF;
        btab_build_kernel<<<1, 256, 0, stream>>>(times_in, decay_rate, aux, n_in);
        fill_tab_kernel<<<256, 256, 0, stream>>>(times_in, seg_ids, aux, tab, n_in);
        if (n_out > 0) {
            conv_fast_kernel<<<grid, BLOCK, 0, stream>>>(
                aux, times_out, pred_ids, decay_rate, kern, bias, out, n_in, n_out);
            conv_gather_kernel<true><<<grid, BLOCK, 0, stream>>>(
                tab, aux, times_in, seg_ids, times_out, pred_ids,
                decay_rate, kern, bias, out, n_in, n_out);
        }
    } else if (n_out > 0) {
        conv_gather_kernel<false><<<grid, BLOCK, 0, stream>>>(
            nullptr, nullptr, times_in, seg_ids, times_out, pred_ids,
            decay_rate, kern, bias, out, n_in, n_out);
    }
}